// Round 9
// baseline (193.950 us; speedup 1.0000x reference)
//
#include <hip/hip_runtime.h>
#include <cstddef>
#include <cstdint>

#define NB 256     // graphs
#define M 512      // nodes per graph
#define KNN 6      // neighbors
#define C 32       // channels

// ---------------------------------------------------------------------------
// Round-19 = round-6 structure (full gather + duplicated full m1, barriers
// 19->10, exchanges deleted) with the spill artifact fixed:
//   __attribute__((amdgpu_waves_per_eu(4,4))) caps occupancy at 4 waves/EU
//   (= our actual 1 block/CU), raising the VGPR budget 64 -> 128 so
//   hm[32]/m1[32] stay in registers. Round-6/7 showed launch_bounds' MIN
//   bound cannot do this (VGPR stayed 64, WRITE_SIZE 4108 KB scratch).
// Scan kept in validated LDS-broadcast form (round-8 readlane was neutral:
// broadcasts are fast-pathed; VALU went up instead).
// All fp chains bit-identical to validated round-4/6: scan dist fma form,
// med3 strict-< ascending insert, gather fmax k=0..5 order, MLP fma i=0..31
// order, relu-fold via 0-init, self-loop union pool identity.
// ---------------------------------------------------------------------------
__global__ __launch_bounds__(1024)
__attribute__((amdgpu_waves_per_eu(4, 4)))
void megafused_kernel(
    const float* __restrict__ x, const float* __restrict__ pos,
    const float* __restrict__ W1a, const float* __restrict__ b1a,
    const float* __restrict__ W2a, const float* __restrict__ b2a,
    const float* __restrict__ W1b, const float* __restrict__ b1b,
    const float* __restrict__ W2b, const float* __restrict__ b2b,
    const float* __restrict__ W1c, const float* __restrict__ b1c,
    const float* __restrict__ W2c, const float* __restrict__ b2c,
    const float* __restrict__ Wr,  const float* __restrict__ br,
    float* __restrict__ out)
{
    __shared__ __align__(16) float Ts[M * C];   // 64 KB, multi-purpose
    const int g  = blockIdx.x;
    const int t  = threadIdx.x;
    const int n  = t & (M - 1);                 // node 0..511
    const int hv = t >> 9;                      // 0/1, wave-uniform
    const int c0 = __builtin_amdgcn_readfirstlane(hv << 4); // SGPR half base

    // ---- overlays within Ts ----
    float4* sp    = (float4*)Ts;            // [0, 8K) B : positions+norms
    float4* lists = (float4*)(Ts + 2048);   // [8K, 40K) B : packed knn lists

    // === phase 0: positions + squared norms into LDS; x prefetched ===
    const float* p = pos + (size_t)g * M * 3;
    if (t < M) {
        float xx = p[3*t], yy = p[3*t+1], zz = p[3*t+2];
        sp[t] = make_float4(xx, yy, zz, fmaf(xx, xx, fmaf(yy, yy, zz * zz)));
    }
    const float h0 = x[(size_t)g * M + n];      // early global load (used in L1)
    __syncthreads();

    const float4 pm = sp[n];

    // === phase 1: KNN scan — row n, cols [hv*256, hv*256+256) ===
    float d0 = INFINITY, d1 = INFINITY, d2 = INFINITY,
          d3 = INFINITY, d4 = INFINITY, d5 = INFINITY;
    int   i0 = -1, i1 = -1, i2 = -1, i3 = -1, i4 = -1, i5 = -1;

    const int col0 = hv << 8;
#pragma unroll 8
    for (int jj = 0; jj < 256; jj++) {
        const int col = col0 + jj;
        const float4 pn = sp[col];                       // wave-uniform broadcast
        float dot  = fmaf(pm.x, pn.x, fmaf(pm.y, pn.y, pm.z * pn.z));
        float dist = fmaf(-2.f, dot, pm.w + pn.w);       // validated rounding chain
        bool c5 = dist < d5, c4 = dist < d4, c3 = dist < d3,
             c2 = dist < d2, c1 = dist < d1, cz = dist < d0;
        i5 = c4 ? i4 : (c5 ? col : i5);
        i4 = c3 ? i3 : (c4 ? col : i4);
        i3 = c2 ? i2 : (c3 ? col : i3);
        i2 = c1 ? i1 : (c2 ? col : i2);
        i1 = cz ? i0 : (c1 ? col : i1);
        i0 = cz ? col : i0;
        d5 = __builtin_amdgcn_fmed3f(dist, d4, d5);
        d4 = __builtin_amdgcn_fmed3f(dist, d3, d4);
        d3 = __builtin_amdgcn_fmed3f(dist, d2, d3);
        d2 = __builtin_amdgcn_fmed3f(dist, d1, d2);
        d1 = __builtin_amdgcn_fmed3f(dist, d0, d1);
        d0 = fminf(dist, d0);
    }

    // publish packed list: {d0..d5, pack(i0,i1,i2), pack(i3,i4,i5)} = 32 B
    {
        unsigned pa = (unsigned)i0 | ((unsigned)i1 << 10) | ((unsigned)i2 << 20);
        unsigned pb = (unsigned)i3 | ((unsigned)i4 << 10) | ((unsigned)i5 << 20);
        lists[2*t]     = make_float4(d0, d1, d2, d3);
        lists[2*t + 1] = make_float4(d4, d5, __uint_as_float(pa), __uint_as_float(pb));
    }
    __syncthreads();

    // === phase 2: merge — base = half-0 list, insert half-1 (tie-stable:
    // half-0 columns have lower indices; strict-< keeps base on ties) ===
    int j[KNN];
    {
        const int pt = t ^ M;                       // partner thread
        const float4 q0 = lists[2*pt], q1 = lists[2*pt + 1];
        const unsigned ppa = __float_as_uint(q1.z), ppb = __float_as_uint(q1.w);

        float md[KNN]; int mi[KNN]; float sd[KNN]; int si[KNN];
        if (c0 == 0) {      // scalar branch: own = half0 (base), partner = half1
            md[0]=d0; md[1]=d1; md[2]=d2; md[3]=d3; md[4]=d4; md[5]=d5;
            mi[0]=i0; mi[1]=i1; mi[2]=i2; mi[3]=i3; mi[4]=i4; mi[5]=i5;
            sd[0]=q0.x; sd[1]=q0.y; sd[2]=q0.z; sd[3]=q0.w; sd[4]=q1.x; sd[5]=q1.y;
            si[0]=(int)(ppa & 1023); si[1]=(int)((ppa >> 10) & 1023); si[2]=(int)((ppa >> 20) & 1023);
            si[3]=(int)(ppb & 1023); si[4]=(int)((ppb >> 10) & 1023); si[5]=(int)((ppb >> 20) & 1023);
        } else {            // own = half1 (insert), partner = half0 (base)
            md[0]=q0.x; md[1]=q0.y; md[2]=q0.z; md[3]=q0.w; md[4]=q1.x; md[5]=q1.y;
            mi[0]=(int)(ppa & 1023); mi[1]=(int)((ppa >> 10) & 1023); mi[2]=(int)((ppa >> 20) & 1023);
            mi[3]=(int)(ppb & 1023); mi[4]=(int)((ppb >> 10) & 1023); mi[5]=(int)((ppb >> 20) & 1023);
            sd[0]=d0; sd[1]=d1; sd[2]=d2; sd[3]=d3; sd[4]=d4; sd[5]=d5;
            si[0]=i0; si[1]=i1; si[2]=i2; si[3]=i3; si[4]=i4; si[5]=i5;
        }
#pragma unroll
        for (int k = 0; k < KNN; k++) {
            const float dist = sd[k];
            const int   nn   = si[k];
            bool c5m = dist < md[5], c4m = dist < md[4], c3m = dist < md[3],
                 c2m = dist < md[2], c1m = dist < md[1], czm = dist < md[0];
            mi[5] = c4m ? mi[4] : (c5m ? nn : mi[5]);
            mi[4] = c3m ? mi[3] : (c4m ? nn : mi[4]);
            mi[3] = c2m ? mi[2] : (c3m ? nn : mi[3]);
            mi[2] = c1m ? mi[1] : (c2m ? nn : mi[2]);
            mi[1] = czm ? mi[0] : (c1m ? nn : mi[1]);
            mi[0] = czm ? nn : mi[0];
            md[5] = __builtin_amdgcn_fmed3f(dist, md[4], md[5]);
            md[4] = __builtin_amdgcn_fmed3f(dist, md[3], md[4]);
            md[3] = __builtin_amdgcn_fmed3f(dist, md[2], md[3]);
            md[2] = __builtin_amdgcn_fmed3f(dist, md[1], md[2]);
            md[1] = __builtin_amdgcn_fmed3f(dist, md[0], md[1]);
            md[0] = fminf(dist, md[0]);
        }
#pragma unroll
        for (int k = 0; k < KNN; k++) j[k] = mi[k];
    }
    __syncthreads();   // partner list reads done; Ts becomes T-staging buffer

    // ---- addressing ----
    // Row layout: full 128 B rows, channel quad q stored at slot (q ^ (row&7)).
    const int ne     = n & 3;
    const int nb_own = (n << 7) + ((hv ^ ((n >> 2) & 1)) << 6);
    char* TsB = (char*)Ts;

    int jb[KNN], jp_[KNN];
#pragma unroll
    for (int k = 0; k < KNN; k++) {
        jb[k]  = j[k] << 7;      // full-row byte base
        jp_[k] = j[k] & 7;       // slot swizzle key
    }

    // === layer 1: T1 = MLP_a([x,pos]) — full m1 (cheap), T half-row ===
    {
        const float h1 = pm.x, h2 = pm.y, h3 = pm.z;
        float m1[C];
#pragma unroll
        for (int o = 0; o < C; o++) {
            float a = b1a[o];
            a = fmaf(W1a[o*4+0], h0, a);
            a = fmaf(W1a[o*4+1], h1, a);
            a = fmaf(W1a[o*4+2], h2, a);
            a = fmaf(W1a[o*4+3], h3, a);
            m1[o] = fmaxf(a, 0.f);
        }
#pragma unroll
        for (int q2 = 0; q2 < 4; q2++) {
            float4 v; float* vp = &v.x;
#pragma unroll
            for (int u = 0; u < 4; u++) {
                const int o = c0 + q2*4 + u;
                float a = b2a[o];
#pragma unroll
                for (int i = 0; i < C; i++) a = fmaf(W2a[o*C + i], m1[i], a);
                vp[u] = a;
            }
            *(float4*)(TsB + nb_own + ((q2 ^ ne) << 4)) = v;
        }
    }
    __syncthreads();

    // === layers 2,3: 2 barriers each ===
#pragma unroll 1
    for (int layer = 0; layer < 2; layer++) {
        const float* W1 = layer ? W1c : W1b;
        const float* b1 = layer ? b1c : b1b;
        const float* W2 = layer ? W2c : W2b;
        const float* b2 = layer ? b2c : b2b;

        // A: aggregate neighbors' FULL rows; 0-init folds the relu (exact)
        float hm[C];
#pragma unroll
        for (int u = 0; u < C; u++) hm[u] = 0.f;
#pragma unroll
        for (int k = 0; k < KNN; k++) {
#pragma unroll
            for (int q = 0; q < 8; q++) {
                const float4 v = *(const float4*)(TsB + jb[k] + ((q ^ jp_[k]) << 4));
                hm[4*q+0] = fmaxf(hm[4*q+0], v.x);
                hm[4*q+1] = fmaxf(hm[4*q+1], v.y);
                hm[4*q+2] = fmaxf(hm[4*q+2], v.z);
                hm[4*q+3] = fmaxf(hm[4*q+3], v.w);
            }
        }
        __syncthreads();              // all T reads done before T overwrite

        // D: m1 FULL (32 outs x 32 ins), duplicated across the two halves
        float m1[C];
#pragma unroll
        for (int o = 0; o < C; o++) {
            float a = b1[o];
#pragma unroll
            for (int i = 0; i < C; i++) a = fmaf(W1[o*C + i], hm[i], a);
            m1[o] = fmaxf(a, 0.f);
        }
        // F: T half-row = W2[c0..c0+15] @ m1 + b2 -> own half of row n
#pragma unroll
        for (int q2 = 0; q2 < 4; q2++) {
            float4 v; float* vp = &v.x;
#pragma unroll
            for (int u = 0; u < 4; u++) {
                const int o = c0 + q2*4 + u;
                float a = b2[o];
#pragma unroll
                for (int i = 0; i < C; i++) a = fmaf(W2[o*C + i], m1[i], a);
                vp[u] = a;
            }
            *(float4*)(TsB + nb_own + ((q2 ^ ne) << 4)) = v;
        }
        __syncthreads();              // T visible
    }

    // === global max pool DIRECTLY over T3 (self-loop union identity,
    // validated round-4/6); relu folded via 0-init (exact) ===
    {
        const int c   = t & 31;        // channel
        const int grp = t >> 5;        // row group 0..31 (16 rows each)
        float m = 0.f;
#pragma unroll
        for (int r16 = 0; r16 < 16; r16++) {
            const int r = (grp << 4) + r16;
            m = fmaxf(m, Ts[(r << 5) + ((((c >> 2) ^ (r & 7)) << 2) | (c & 3))]);
        }
        __syncthreads();               // all T3 reads done
        Ts[(grp << 5) + (c ^ grp)] = m;          // conflict-free partial store
        __syncthreads();
        if (t < 32) {                  // wave 0: 32 lanes finish the pool
            float mm = 0.f;
#pragma unroll
            for (int g2 = 0; g2 < 32; g2++)
                mm = fmaxf(mm, Ts[(g2 << 5) + (t ^ g2)]);
            Ts[t] = mm;                // word t read only by this lane (g2=0 first)
        }
        __syncthreads();
    }

    // === head ===
    if (t < 6) {
        float a = br[t];
#pragma unroll
        for (int i = 0; i < C; i++) a = fmaf(Wr[t*C + i], Ts[i], a);
        out[g * 6 + t] = a;
    }
}

extern "C" void kernel_launch(void* const* d_in, const int* in_sizes, int n_in,
                              void* d_out, int out_size, void* d_ws, size_t ws_size,
                              hipStream_t stream) {
    const float* x   = (const float*)d_in[0];
    const float* pos = (const float*)d_in[1];
    // d_in[2] = batch (int64) unused: nodes are contiguous M-per-graph
    const float* W1a = (const float*)d_in[3];
    const float* b1a = (const float*)d_in[4];
    const float* W2a = (const float*)d_in[5];
    const float* b2a = (const float*)d_in[6];
    const float* W1b = (const float*)d_in[7];
    const float* b1b = (const float*)d_in[8];
    const float* W2b = (const float*)d_in[9];
    const float* b2b = (const float*)d_in[10];
    const float* W1c = (const float*)d_in[11];
    const float* b1c = (const float*)d_in[12];
    const float* W2c = (const float*)d_in[13];
    const float* b2c = (const float*)d_in[14];
    const float* Wr  = (const float*)d_in[15];
    const float* br  = (const float*)d_in[16];

    float* out = (float*)d_out;

    megafused_kernel<<<NB, 1024, 0, stream>>>(x, pos,
                                              W1a, b1a, W2a, b2a,
                                              W1b, b1b, W2b, b2b,
                                              W1c, b1c, W2c, b2c,
                                              Wr, br, out);
}

// Round 10
// 193.473 us; speedup vs baseline: 1.0025x; 1.0025x over previous
//
#include <hip/hip_runtime.h>
#include <cstddef>
#include <cstdint>

#define NB 256     // graphs
#define M 512      // nodes per graph
#define KNN 6      // neighbors
#define C 32       // channels

// ---------------------------------------------------------------------------
// Round-20 = round-6 structure (full gather + duplicated full m1, barriers
// 19->10, exchanges deleted) with the spill fixed at its ROOT:
//   LDS padded 64 KB -> 96 KB. 64 KB allows 2 blocks/CU (160/64), so the
//   compiler targeted 8 waves/EU and capped VGPR at 64, spilling hm[32]/m1[32]
//   (WRITE_SIZE 4108-6156 KB in r6/7/9; launch_bounds(,4) and
//   amdgpu_waves_per_eu(4,4) both failed to override the heuristic).
//   96 KB makes 1 block/CU the compiler's own occupancy bound -> 4 waves/EU
//   -> 128-VGPR budget -> no spill. Grid = 256 = 1 block/CU anyway, so no
//   real occupancy is lost. All overlays live in the first 64 KB.
// All fp chains bit-identical to validated round-6 (absmax 0.0): scan dist
// fma form, med3 strict-< ascending insert, gather fmax k=0..5 order, MLP
// fma i=0..31 order, relu-fold via 0-init, self-loop union pool identity.
// ---------------------------------------------------------------------------
__global__ __launch_bounds__(1024, 1) void megafused_kernel(
    const float* __restrict__ x, const float* __restrict__ pos,
    const float* __restrict__ W1a, const float* __restrict__ b1a,
    const float* __restrict__ W2a, const float* __restrict__ b2a,
    const float* __restrict__ W1b, const float* __restrict__ b1b,
    const float* __restrict__ W2b, const float* __restrict__ b2b,
    const float* __restrict__ W1c, const float* __restrict__ b1c,
    const float* __restrict__ W2c, const float* __restrict__ b2c,
    const float* __restrict__ Wr,  const float* __restrict__ br,
    float* __restrict__ out)
{
    // 96 KB static LDS: first 64 KB used as before; 32 KB tail is padding
    // whose sole purpose is to cap occupancy at 1 block/CU in the compiler's
    // VGPR-budget heuristic (see header comment).
    __shared__ __align__(16) float Ts[M * C + 8192];
    const int g  = blockIdx.x;
    const int t  = threadIdx.x;
    const int n  = t & (M - 1);                 // node 0..511
    const int hv = t >> 9;                      // 0/1, wave-uniform
    const int c0 = __builtin_amdgcn_readfirstlane(hv << 4); // SGPR half base

    // ---- overlays within Ts ----
    float4* sp    = (float4*)Ts;            // [0, 8K) B : positions+norms
    float4* lists = (float4*)(Ts + 2048);   // [8K, 40K) B : packed knn lists

    // === phase 0: positions + squared norms into LDS; x prefetched ===
    const float* p = pos + (size_t)g * M * 3;
    if (t < M) {
        float xx = p[3*t], yy = p[3*t+1], zz = p[3*t+2];
        sp[t] = make_float4(xx, yy, zz, fmaf(xx, xx, fmaf(yy, yy, zz * zz)));
    }
    const float h0 = x[(size_t)g * M + n];      // early global load (used in L1)
    __syncthreads();

    const float4 pm = sp[n];

    // === phase 1: KNN scan — row n, cols [hv*256, hv*256+256) ===
    float d0 = INFINITY, d1 = INFINITY, d2 = INFINITY,
          d3 = INFINITY, d4 = INFINITY, d5 = INFINITY;
    int   i0 = -1, i1 = -1, i2 = -1, i3 = -1, i4 = -1, i5 = -1;

    const int col0 = hv << 8;
#pragma unroll 8
    for (int jj = 0; jj < 256; jj++) {
        const int col = col0 + jj;
        const float4 pn = sp[col];                       // wave-uniform broadcast
        float dot  = fmaf(pm.x, pn.x, fmaf(pm.y, pn.y, pm.z * pn.z));
        float dist = fmaf(-2.f, dot, pm.w + pn.w);       // validated rounding chain
        bool c5 = dist < d5, c4 = dist < d4, c3 = dist < d3,
             c2 = dist < d2, c1 = dist < d1, cz = dist < d0;
        i5 = c4 ? i4 : (c5 ? col : i5);
        i4 = c3 ? i3 : (c4 ? col : i4);
        i3 = c2 ? i2 : (c3 ? col : i3);
        i2 = c1 ? i1 : (c2 ? col : i2);
        i1 = cz ? i0 : (c1 ? col : i1);
        i0 = cz ? col : i0;
        d5 = __builtin_amdgcn_fmed3f(dist, d4, d5);
        d4 = __builtin_amdgcn_fmed3f(dist, d3, d4);
        d3 = __builtin_amdgcn_fmed3f(dist, d2, d3);
        d2 = __builtin_amdgcn_fmed3f(dist, d1, d2);
        d1 = __builtin_amdgcn_fmed3f(dist, d0, d1);
        d0 = fminf(dist, d0);
    }

    // publish packed list: {d0..d5, pack(i0,i1,i2), pack(i3,i4,i5)} = 32 B
    {
        unsigned pa = (unsigned)i0 | ((unsigned)i1 << 10) | ((unsigned)i2 << 20);
        unsigned pb = (unsigned)i3 | ((unsigned)i4 << 10) | ((unsigned)i5 << 20);
        lists[2*t]     = make_float4(d0, d1, d2, d3);
        lists[2*t + 1] = make_float4(d4, d5, __uint_as_float(pa), __uint_as_float(pb));
    }
    __syncthreads();

    // === phase 2: merge — base = half-0 list, insert half-1 (tie-stable:
    // half-0 columns have lower indices; strict-< keeps base on ties) ===
    int j[KNN];
    {
        const int pt = t ^ M;                       // partner thread
        const float4 q0 = lists[2*pt], q1 = lists[2*pt + 1];
        const unsigned ppa = __float_as_uint(q1.z), ppb = __float_as_uint(q1.w);

        float md[KNN]; int mi[KNN]; float sd[KNN]; int si[KNN];
        if (c0 == 0) {      // scalar branch: own = half0 (base), partner = half1
            md[0]=d0; md[1]=d1; md[2]=d2; md[3]=d3; md[4]=d4; md[5]=d5;
            mi[0]=i0; mi[1]=i1; mi[2]=i2; mi[3]=i3; mi[4]=i4; mi[5]=i5;
            sd[0]=q0.x; sd[1]=q0.y; sd[2]=q0.z; sd[3]=q0.w; sd[4]=q1.x; sd[5]=q1.y;
            si[0]=(int)(ppa & 1023); si[1]=(int)((ppa >> 10) & 1023); si[2]=(int)((ppa >> 20) & 1023);
            si[3]=(int)(ppb & 1023); si[4]=(int)((ppb >> 10) & 1023); si[5]=(int)((ppb >> 20) & 1023);
        } else {            // own = half1 (insert), partner = half0 (base)
            md[0]=q0.x; md[1]=q0.y; md[2]=q0.z; md[3]=q0.w; md[4]=q1.x; md[5]=q1.y;
            mi[0]=(int)(ppa & 1023); mi[1]=(int)((ppa >> 10) & 1023); mi[2]=(int)((ppa >> 20) & 1023);
            mi[3]=(int)(ppb & 1023); mi[4]=(int)((ppb >> 10) & 1023); mi[5]=(int)((ppb >> 20) & 1023);
            sd[0]=d0; sd[1]=d1; sd[2]=d2; sd[3]=d3; sd[4]=d4; sd[5]=d5;
            si[0]=i0; si[1]=i1; si[2]=i2; si[3]=i3; si[4]=i4; si[5]=i5;
        }
#pragma unroll
        for (int k = 0; k < KNN; k++) {
            const float dist = sd[k];
            const int   nn   = si[k];
            bool c5m = dist < md[5], c4m = dist < md[4], c3m = dist < md[3],
                 c2m = dist < md[2], c1m = dist < md[1], czm = dist < md[0];
            mi[5] = c4m ? mi[4] : (c5m ? nn : mi[5]);
            mi[4] = c3m ? mi[3] : (c4m ? nn : mi[4]);
            mi[3] = c2m ? mi[2] : (c3m ? nn : mi[3]);
            mi[2] = c1m ? mi[1] : (c2m ? nn : mi[2]);
            mi[1] = czm ? mi[0] : (c1m ? nn : mi[1]);
            mi[0] = czm ? nn : mi[0];
            md[5] = __builtin_amdgcn_fmed3f(dist, md[4], md[5]);
            md[4] = __builtin_amdgcn_fmed3f(dist, md[3], md[4]);
            md[3] = __builtin_amdgcn_fmed3f(dist, md[2], md[3]);
            md[2] = __builtin_amdgcn_fmed3f(dist, md[1], md[2]);
            md[1] = __builtin_amdgcn_fmed3f(dist, md[0], md[1]);
            md[0] = fminf(dist, md[0]);
        }
#pragma unroll
        for (int k = 0; k < KNN; k++) j[k] = mi[k];
    }
    __syncthreads();   // partner list reads done; Ts becomes T-staging buffer

    // ---- addressing ----
    // Row layout: full 128 B rows, channel quad q stored at slot (q ^ (row&7)).
    const int ne     = n & 3;
    const int nb_own = (n << 7) + ((hv ^ ((n >> 2) & 1)) << 6);
    char* TsB = (char*)Ts;

    int jb[KNN], jp_[KNN];
#pragma unroll
    for (int k = 0; k < KNN; k++) {
        jb[k]  = j[k] << 7;      // full-row byte base
        jp_[k] = j[k] & 7;       // slot swizzle key
    }

    // === layer 1: T1 = MLP_a([x,pos]) — full m1 (cheap), T half-row ===
    {
        const float h1 = pm.x, h2 = pm.y, h3 = pm.z;
        float m1[C];
#pragma unroll
        for (int o = 0; o < C; o++) {
            float a = b1a[o];
            a = fmaf(W1a[o*4+0], h0, a);
            a = fmaf(W1a[o*4+1], h1, a);
            a = fmaf(W1a[o*4+2], h2, a);
            a = fmaf(W1a[o*4+3], h3, a);
            m1[o] = fmaxf(a, 0.f);
        }
#pragma unroll
        for (int q2 = 0; q2 < 4; q2++) {
            float4 v; float* vp = &v.x;
#pragma unroll
            for (int u = 0; u < 4; u++) {
                const int o = c0 + q2*4 + u;
                float a = b2a[o];
#pragma unroll
                for (int i = 0; i < C; i++) a = fmaf(W2a[o*C + i], m1[i], a);
                vp[u] = a;
            }
            *(float4*)(TsB + nb_own + ((q2 ^ ne) << 4)) = v;
        }
    }
    __syncthreads();

    // === layers 2,3: 2 barriers each ===
#pragma unroll 1
    for (int layer = 0; layer < 2; layer++) {
        const float* W1 = layer ? W1c : W1b;
        const float* b1 = layer ? b1c : b1b;
        const float* W2 = layer ? W2c : W2b;
        const float* b2 = layer ? b2c : b2b;

        // A: aggregate neighbors' FULL rows; 0-init folds the relu (exact)
        float hm[C];
#pragma unroll
        for (int u = 0; u < C; u++) hm[u] = 0.f;
#pragma unroll
        for (int k = 0; k < KNN; k++) {
#pragma unroll
            for (int q = 0; q < 8; q++) {
                const float4 v = *(const float4*)(TsB + jb[k] + ((q ^ jp_[k]) << 4));
                hm[4*q+0] = fmaxf(hm[4*q+0], v.x);
                hm[4*q+1] = fmaxf(hm[4*q+1], v.y);
                hm[4*q+2] = fmaxf(hm[4*q+2], v.z);
                hm[4*q+3] = fmaxf(hm[4*q+3], v.w);
            }
        }
        __syncthreads();              // all T reads done before T overwrite

        // D: m1 FULL (32 outs x 32 ins), duplicated across the two halves
        float m1[C];
#pragma unroll
        for (int o = 0; o < C; o++) {
            float a = b1[o];
#pragma unroll
            for (int i = 0; i < C; i++) a = fmaf(W1[o*C + i], hm[i], a);
            m1[o] = fmaxf(a, 0.f);
        }
        // F: T half-row = W2[c0..c0+15] @ m1 + b2 -> own half of row n
#pragma unroll
        for (int q2 = 0; q2 < 4; q2++) {
            float4 v; float* vp = &v.x;
#pragma unroll
            for (int u = 0; u < 4; u++) {
                const int o = c0 + q2*4 + u;
                float a = b2[o];
#pragma unroll
                for (int i = 0; i < C; i++) a = fmaf(W2[o*C + i], m1[i], a);
                vp[u] = a;
            }
            *(float4*)(TsB + nb_own + ((q2 ^ ne) << 4)) = v;
        }
        __syncthreads();              // T visible
    }

    // === global max pool DIRECTLY over T3 (self-loop union identity,
    // validated round-4/6); relu folded via 0-init (exact) ===
    {
        const int c   = t & 31;        // channel
        const int grp = t >> 5;        // row group 0..31 (16 rows each)
        float m = 0.f;
#pragma unroll
        for (int r16 = 0; r16 < 16; r16++) {
            const int r = (grp << 4) + r16;
            m = fmaxf(m, Ts[(r << 5) + ((((c >> 2) ^ (r & 7)) << 2) | (c & 3))]);
        }
        __syncthreads();               // all T3 reads done
        Ts[(grp << 5) + (c ^ grp)] = m;          // conflict-free partial store
        __syncthreads();
        if (t < 32) {                  // wave 0: 32 lanes finish the pool
            float mm = 0.f;
#pragma unroll
            for (int g2 = 0; g2 < 32; g2++)
                mm = fmaxf(mm, Ts[(g2 << 5) + (t ^ g2)]);
            Ts[t] = mm;                // word t read only by this lane (g2=0 first)
        }
        __syncthreads();
    }

    // === head ===
    if (t < 6) {
        float a = br[t];
#pragma unroll
        for (int i = 0; i < C; i++) a = fmaf(Wr[t*C + i], Ts[i], a);
        out[g * 6 + t] = a;
    }
}

extern "C" void kernel_launch(void* const* d_in, const int* in_sizes, int n_in,
                              void* d_out, int out_size, void* d_ws, size_t ws_size,
                              hipStream_t stream) {
    const float* x   = (const float*)d_in[0];
    const float* pos = (const float*)d_in[1];
    // d_in[2] = batch (int64) unused: nodes are contiguous M-per-graph
    const float* W1a = (const float*)d_in[3];
    const float* b1a = (const float*)d_in[4];
    const float* W2a = (const float*)d_in[5];
    const float* b2a = (const float*)d_in[6];
    const float* W1b = (const float*)d_in[7];
    const float* b1b = (const float*)d_in[8];
    const float* W2b = (const float*)d_in[9];
    const float* b2b = (const float*)d_in[10];
    const float* W1c = (const float*)d_in[11];
    const float* b1c = (const float*)d_in[12];
    const float* W2c = (const float*)d_in[13];
    const float* b2c = (const float*)d_in[14];
    const float* Wr  = (const float*)d_in[15];
    const float* br  = (const float*)d_in[16];

    float* out = (float*)d_out;

    megafused_kernel<<<NB, 1024, 0, stream>>>(x, pos,
                                              W1a, b1a, W2a, b2a,
                                              W1b, b1b, W2b, b2b,
                                              W1c, b1c, W2c, b2c,
                                              Wr, br, out);
}

// Round 11
// 174.933 us; speedup vs baseline: 1.1087x; 1.1060x over previous
//
#include <hip/hip_runtime.h>
#include <cstddef>
#include <cstdint>

#define NB 256     // graphs
#define M 512      // nodes per graph
#define KNN 6      // neighbors
#define C 32       // channels

// ---------------------------------------------------------------------------
// Round-21 = round-4 base (validated 172.9us, VGPR 52, no spill) with two
// orthogonal structural cuts, both liveness-neutral:
//  (1) scan candidates read from a global float4 {x,y,z,|p|^2} table built by
//      a tiny pre-kernel (norm fma chain identical to old phase-0). Address
//      is wave-uniform (derived from readfirstlane'd c0) -> scalar/broadcast
//      path, freeing the per-CU LDS pipe during the dominant scan phase
//      (256 of ~380 LDS ops/wave deleted).
//  (2) TWO 64 KB LDS buffers (128 KB total; 96 KB proven in r10): T-in and
//      h/m1 staging never alias -> 3 barriers/layer instead of 6, merge and
//      pool barriers trimmed: 19 -> 10 barriers. Phase bodies byte-identical
//      to round-4 (same half-gather => same conflicts, same ~52-VGPR
//      liveness => no spill, unlike r6-r10's full-gather attempts).
// Fallback template<false> (ws too small): in-LDS scan + the 11-barrier
// two-buffer layout.
// All fp chains bit-identical to round-4: scan dist fma form + candidate
// order, med3 strict-< ascending insert, gather fmax k=0..5 order, MLP fma
// i=0..31 order, relu-fold via 0-init, self-loop union pool identity.
// ---------------------------------------------------------------------------

__global__ __launch_bounds__(512, 1) void build_table_kernel(
    const float* __restrict__ pos, float4* __restrict__ tab)
{
    const int i = blockIdx.x * 512 + threadIdx.x;      // 0 .. NB*M-1
    const float xx = pos[3*i], yy = pos[3*i+1], zz = pos[3*i+2];
    tab[i] = make_float4(xx, yy, zz, fmaf(xx, xx, fmaf(yy, yy, zz * zz)));
}

template <bool USE_TAB>
__global__ __launch_bounds__(1024, 1) void megafused_kernel(
    const float* __restrict__ x, const float* __restrict__ pos,
    const float4* __restrict__ tab,
    const float* __restrict__ W1a, const float* __restrict__ b1a,
    const float* __restrict__ W2a, const float* __restrict__ b2a,
    const float* __restrict__ W1b, const float* __restrict__ b1b,
    const float* __restrict__ W2b, const float* __restrict__ b2b,
    const float* __restrict__ W1c, const float* __restrict__ b1c,
    const float* __restrict__ W2c, const float* __restrict__ b2c,
    const float* __restrict__ Wr,  const float* __restrict__ br,
    float* __restrict__ out)
{
    __shared__ __align__(16) float Pbuf[M * C];   // 64 KB: T1, m1(L3), T3
    __shared__ __align__(16) float Qbuf[M * C];   // 64 KB: sp/lists, h, m1(L2), T2, pool
    const int g  = blockIdx.x;
    const int t  = threadIdx.x;
    const int n  = t & (M - 1);                 // node 0..511
    const int hv = t >> 9;                      // 0/1, wave-uniform
    const int c0 = __builtin_amdgcn_readfirstlane(hv << 4); // SGPR half base

    float4* sp    = (float4*)Qbuf;            // [0, 8K) B of Q (fallback only)
    float4* lists = (float4*)(Qbuf + 2048);   // [8K, 40K) B of Q

    // === phase 0 ===
    const float4* tabg = tab + (size_t)g * M;
    float4 pm;
    if constexpr (USE_TAB) {
        pm = tabg[n];                          // per-lane vector load (L2)
    } else {
        const float* p = pos + (size_t)g * M * 3;
        if (t < M) {
            float xx = p[3*t], yy = p[3*t+1], zz = p[3*t+2];
            sp[t] = make_float4(xx, yy, zz, fmaf(xx, xx, fmaf(yy, yy, zz * zz)));
        }
    }
    const float h0 = x[(size_t)g * M + n];     // early global load (used in L1)
    if constexpr (!USE_TAB) { __syncthreads(); pm = sp[n]; }

    // === phase 1: KNN scan — row n, cols [hv*256, hv*256+256) ===
    float d0 = INFINITY, d1 = INFINITY, d2 = INFINITY,
          d3 = INFINITY, d4 = INFINITY, d5 = INFINITY;
    int   i0 = -1, i1 = -1, i2 = -1, i3 = -1, i4 = -1, i5 = -1;

#pragma unroll 8
    for (int jj = 0; jj < 256; jj++) {
        const int col = (c0 << 4) + jj;        // uniform provenance (c0 is SGPR)
        float4 pn;
        if constexpr (USE_TAB) pn = tabg[col]; // scalar/broadcast load, no LDS
        else                   pn = sp[col];   // wave-uniform LDS broadcast
        float dot  = fmaf(pm.x, pn.x, fmaf(pm.y, pn.y, pm.z * pn.z));
        float dist = fmaf(-2.f, dot, pm.w + pn.w);       // validated rounding chain
        bool c5 = dist < d5, c4 = dist < d4, c3 = dist < d3,
             c2 = dist < d2, c1 = dist < d1, cz = dist < d0;
        i5 = c4 ? i4 : (c5 ? col : i5);
        i4 = c3 ? i3 : (c4 ? col : i4);
        i3 = c2 ? i2 : (c3 ? col : i3);
        i2 = c1 ? i1 : (c2 ? col : i2);
        i1 = cz ? i0 : (c1 ? col : i1);
        i0 = cz ? col : i0;
        d5 = __builtin_amdgcn_fmed3f(dist, d4, d5);
        d4 = __builtin_amdgcn_fmed3f(dist, d3, d4);
        d3 = __builtin_amdgcn_fmed3f(dist, d2, d3);
        d2 = __builtin_amdgcn_fmed3f(dist, d1, d2);
        d1 = __builtin_amdgcn_fmed3f(dist, d0, d1);
        d0 = fminf(dist, d0);
    }

    // publish packed list: {d0..d5, pack(i0,i1,i2), pack(i3,i4,i5)} = 32 B
    {
        unsigned pa = (unsigned)i0 | ((unsigned)i1 << 10) | ((unsigned)i2 << 20);
        unsigned pb = (unsigned)i3 | ((unsigned)i4 << 10) | ((unsigned)i5 << 20);
        lists[2*t]     = make_float4(d0, d1, d2, d3);
        lists[2*t + 1] = make_float4(d4, d5, __uint_as_float(pa), __uint_as_float(pb));
    }
    __syncthreads();                           // [bar] lists visible

    // === phase 2: merge — base = half-0 list, insert half-1 (tie-stable:
    // half-0 columns have lower indices; strict-< keeps base on ties) ===
    int j[KNN];
    {
        const int pt = t ^ M;                       // partner thread
        const float4 q0 = lists[2*pt], q1 = lists[2*pt + 1];
        const unsigned ppa = __float_as_uint(q1.z), ppb = __float_as_uint(q1.w);

        float md[KNN]; int mi[KNN]; float sd[KNN]; int si[KNN];
        if (c0 == 0) {      // scalar branch: own = half0 (base), partner = half1
            md[0]=d0; md[1]=d1; md[2]=d2; md[3]=d3; md[4]=d4; md[5]=d5;
            mi[0]=i0; mi[1]=i1; mi[2]=i2; mi[3]=i3; mi[4]=i4; mi[5]=i5;
            sd[0]=q0.x; sd[1]=q0.y; sd[2]=q0.z; sd[3]=q0.w; sd[4]=q1.x; sd[5]=q1.y;
            si[0]=(int)(ppa & 1023); si[1]=(int)((ppa >> 10) & 1023); si[2]=(int)((ppa >> 20) & 1023);
            si[3]=(int)(ppb & 1023); si[4]=(int)((ppb >> 10) & 1023); si[5]=(int)((ppb >> 20) & 1023);
        } else {            // own = half1 (insert), partner = half0 (base)
            md[0]=q0.x; md[1]=q0.y; md[2]=q0.z; md[3]=q0.w; md[4]=q1.x; md[5]=q1.y;
            mi[0]=(int)(ppa & 1023); mi[1]=(int)((ppa >> 10) & 1023); mi[2]=(int)((ppa >> 20) & 1023);
            mi[3]=(int)(ppb & 1023); mi[4]=(int)((ppb >> 10) & 1023); mi[5]=(int)((ppb >> 20) & 1023);
            sd[0]=d0; sd[1]=d1; sd[2]=d2; sd[3]=d3; sd[4]=d4; sd[5]=d5;
            si[0]=i0; si[1]=i1; si[2]=i2; si[3]=i3; si[4]=i4; si[5]=i5;
        }
#pragma unroll
        for (int k = 0; k < KNN; k++) {
            const float dist = sd[k];
            const int   nn   = si[k];
            bool c5m = dist < md[5], c4m = dist < md[4], c3m = dist < md[3],
                 c2m = dist < md[2], c1m = dist < md[1], czm = dist < md[0];
            mi[5] = c4m ? mi[4] : (c5m ? nn : mi[5]);
            mi[4] = c3m ? mi[3] : (c4m ? nn : mi[4]);
            mi[3] = c2m ? mi[2] : (c3m ? nn : mi[3]);
            mi[2] = c1m ? mi[1] : (c2m ? nn : mi[2]);
            mi[1] = czm ? mi[0] : (c1m ? nn : mi[1]);
            mi[0] = czm ? nn : mi[0];
            md[5] = __builtin_amdgcn_fmed3f(dist, md[4], md[5]);
            md[4] = __builtin_amdgcn_fmed3f(dist, md[3], md[4]);
            md[3] = __builtin_amdgcn_fmed3f(dist, md[2], md[3]);
            md[2] = __builtin_amdgcn_fmed3f(dist, md[1], md[2]);
            md[1] = __builtin_amdgcn_fmed3f(dist, md[0], md[1]);
            md[0] = fminf(dist, md[0]);
        }
#pragma unroll
        for (int k = 0; k < KNN; k++) j[k] = mi[k];
    }
    // no barrier: lists (Q) are not overwritten until layer-2 phase B, which
    // is ordered after the T1-visible barrier below (program order per thread)

    // ---- precomputed addressing (byte offsets, round-4 formulas) ----
    const int ne     = n & 3;
    const int nb_own = (n << 7) + ((hv ^ ((n >> 2) & 1)) << 6);
    const int nb_par = nb_own ^ 64;

    int jb[KNN], je[KNN];
#pragma unroll
    for (int k = 0; k < KNN; k++) {
        const int jl = j[k];
        jb[k] = (jl << 7) + ((hv ^ ((jl >> 2) & 1)) << 6);
        je[k] = jl & 3;
    }

    // === layer 1: T1 = MLP_a([x,pos]) -> P ===
    {
        const float h1 = pm.x, h2 = pm.y, h3 = pm.z;
        float m1[C];
#pragma unroll
        for (int o = 0; o < C; o++) {
            float a = b1a[o];
            a = fmaf(W1a[o*4+0], h0, a);
            a = fmaf(W1a[o*4+1], h1, a);
            a = fmaf(W1a[o*4+2], h2, a);
            a = fmaf(W1a[o*4+3], h3, a);
            m1[o] = fmaxf(a, 0.f);
        }
#pragma unroll
        for (int q2 = 0; q2 < 4; q2++) {
            float4 v; float* vp = &v.x;
#pragma unroll
            for (int u = 0; u < 4; u++) {
                const int o = c0 + q2*4 + u;
                float a = b2a[o];
#pragma unroll
                for (int i = 0; i < C; i++) a = fmaf(W2a[o*C + i], m1[i], a);
                vp[u] = a;
            }
            *(float4*)((char*)Pbuf + nb_own + ((q2 ^ ne) << 4)) = v;
        }
    }
    __syncthreads();                           // [bar] T1 visible; lists dead

    // === layers 2,3: 3 barriers each; src holds T_in, dst holds h then T_out,
    // m1 staged into src (T_in dead after the h barrier) ===
#pragma unroll 1
    for (int layer = 0; layer < 2; layer++) {
        const float* W1 = layer ? W1c : W1b;
        const float* b1 = layer ? b1c : b1b;
        const float* W2 = layer ? W2c : W2b;
        const float* b2 = layer ? b2c : b2b;
        char* src = (char*)(layer ? Qbuf : Pbuf);   // T_in; then m1 staging
        char* dst = (char*)(layer ? Pbuf : Qbuf);   // h staging; then T_out

        // A: aggregate neighbors' half-rows from src; 0-init folds relu (exact)
        float hm[16];
#pragma unroll
        for (int u = 0; u < 16; u++) hm[u] = 0.f;
#pragma unroll
        for (int k = 0; k < KNN; k++) {
#pragma unroll
            for (int q2 = 0; q2 < 4; q2++) {
                const float4 v = *(const float4*)(src + jb[k] + ((q2 ^ je[k]) << 4));
                hm[4*q2+0] = fmaxf(hm[4*q2+0], v.x);
                hm[4*q2+1] = fmaxf(hm[4*q2+1], v.y);
                hm[4*q2+2] = fmaxf(hm[4*q2+2], v.z);
                hm[4*q2+3] = fmaxf(hm[4*q2+3], v.w);
            }
        }
        // B: write h half-row to dst (no alias with src reads)
#pragma unroll
        for (int q2 = 0; q2 < 4; q2++)
            *(float4*)(dst + nb_own + ((q2 ^ ne) << 4)) =
                make_float4(hm[4*q2+0], hm[4*q2+1], hm[4*q2+2], hm[4*q2+3]);
        __syncthreads();              // [bar] h visible; all T_in reads done
        // C: own half from regs, read only PARTNER's 4 quads from dst
        float hf[C];
        if (c0 == 0) {
#pragma unroll
            for (int u = 0; u < 16; u++) hf[u] = hm[u];
#pragma unroll
            for (int q2 = 0; q2 < 4; q2++) {
                const float4 v = *(const float4*)(dst + nb_par + ((q2 ^ ne) << 4));
                hf[16+4*q2+0]=v.x; hf[16+4*q2+1]=v.y; hf[16+4*q2+2]=v.z; hf[16+4*q2+3]=v.w;
            }
        } else {
#pragma unroll
            for (int u = 0; u < 16; u++) hf[16+u] = hm[u];
#pragma unroll
            for (int q2 = 0; q2 < 4; q2++) {
                const float4 v = *(const float4*)(dst + nb_par + ((q2 ^ ne) << 4));
                hf[4*q2+0]=v.x; hf[4*q2+1]=v.y; hf[4*q2+2]=v.z; hf[4*q2+3]=v.w;
            }
        }
        // D: m1 HALF (16 outs x 32 ins) -> stage into src (T_in dead)
        float m1h[16];
#pragma unroll
        for (int o2 = 0; o2 < 16; o2++) {
            const int o = c0 + o2;
            float a = b1[o];
#pragma unroll
            for (int i = 0; i < C; i++) a = fmaf(W1[o*C + i], hf[i], a);
            m1h[o2] = fmaxf(a, 0.f);
        }
#pragma unroll
        for (int q2 = 0; q2 < 4; q2++)
            *(float4*)(src + nb_own + ((q2 ^ ne) << 4)) =
                make_float4(m1h[4*q2+0], m1h[4*q2+1], m1h[4*q2+2], m1h[4*q2+3]);
        __syncthreads();              // [bar] m1 visible; all h reads done
        // E: own half from regs, read only PARTNER's 4 quads from src
        float m1f[C];
        if (c0 == 0) {
#pragma unroll
            for (int u = 0; u < 16; u++) m1f[u] = m1h[u];
#pragma unroll
            for (int q2 = 0; q2 < 4; q2++) {
                const float4 v = *(const float4*)(src + nb_par + ((q2 ^ ne) << 4));
                m1f[16+4*q2+0]=v.x; m1f[16+4*q2+1]=v.y; m1f[16+4*q2+2]=v.z; m1f[16+4*q2+3]=v.w;
            }
        } else {
#pragma unroll
            for (int u = 0; u < 16; u++) m1f[16+u] = m1h[u];
#pragma unroll
            for (int q2 = 0; q2 < 4; q2++) {
                const float4 v = *(const float4*)(src + nb_par + ((q2 ^ ne) << 4));
                m1f[4*q2+0]=v.x; m1f[4*q2+1]=v.y; m1f[4*q2+2]=v.z; m1f[4*q2+3]=v.w;
            }
        }
        // F: T_out half-row -> dst (h region dead: all C reads done at m1 bar)
#pragma unroll
        for (int q2 = 0; q2 < 4; q2++) {
            float4 v; float* vp = &v.x;
#pragma unroll
            for (int u = 0; u < 4; u++) {
                const int o = c0 + q2*4 + u;
                float a = b2[o];
#pragma unroll
                for (int i = 0; i < C; i++) a = fmaf(W2[o*C + i], m1f[i], a);
                vp[u] = a;
            }
            *(float4*)(dst + nb_own + ((q2 ^ ne) << 4)) = v;
        }
        __syncthreads();              // [bar] T_out visible
    }
    // T2 -> Q (layer 0), T3 -> P (layer 1); pool reads P, scratches Q.

    // === global max pool DIRECTLY over T3 (self-loop union identity,
    // validated round-4); relu folded via 0-init (exact) ===
    {
        const int c   = t & 31;        // channel
        const int grp = t >> 5;        // row group 0..31 (16 rows each)
        float m = 0.f;
#pragma unroll
        for (int r16 = 0; r16 < 16; r16++) {
            const int r = (grp << 4) + r16;
            m = fmaxf(m, Pbuf[(r << 5) + ((((c >> 2) ^ (r & 7)) << 2) | (c & 3))]);
        }
        Qbuf[(grp << 5) + (c ^ grp)] = m;        // partial -> Q (no alias w/ P reads)
        __syncthreads();               // [bar] partials visible
        if (t < 32) {                  // wave 0: 32 lanes finish the pool
            float mm = 0.f;
#pragma unroll
            for (int g2 = 0; g2 < 32; g2++)
                mm = fmaxf(mm, Qbuf[(g2 << 5) + (t ^ g2)]);
            Qbuf[t] = mm;              // word t read first by lane t only (g2=0)
        }
        __syncthreads();               // [bar] finals visible
    }

    // === head ===
    if (t < 6) {
        float a = br[t];
#pragma unroll
        for (int i = 0; i < C; i++) a = fmaf(Wr[t*C + i], Qbuf[i], a);
        out[g * 6 + t] = a;
    }
}

extern "C" void kernel_launch(void* const* d_in, const int* in_sizes, int n_in,
                              void* d_out, int out_size, void* d_ws, size_t ws_size,
                              hipStream_t stream) {
    const float* x   = (const float*)d_in[0];
    const float* pos = (const float*)d_in[1];
    // d_in[2] = batch (int64) unused: nodes are contiguous M-per-graph
    const float* W1a = (const float*)d_in[3];
    const float* b1a = (const float*)d_in[4];
    const float* W2a = (const float*)d_in[5];
    const float* b2a = (const float*)d_in[6];
    const float* W1b = (const float*)d_in[7];
    const float* b1b = (const float*)d_in[8];
    const float* W2b = (const float*)d_in[9];
    const float* b2b = (const float*)d_in[10];
    const float* W1c = (const float*)d_in[11];
    const float* b1c = (const float*)d_in[12];
    const float* W2c = (const float*)d_in[13];
    const float* b2c = (const float*)d_in[14];
    const float* Wr  = (const float*)d_in[15];
    const float* br  = (const float*)d_in[16];

    float* out = (float*)d_out;
    float4* tab = (float4*)d_ws;
    const bool use_tab = (d_ws != nullptr) &&
                         (ws_size >= sizeof(float4) * (size_t)NB * M);

    if (use_tab) {
        build_table_kernel<<<NB, 512, 0, stream>>>(pos, tab);
        megafused_kernel<true><<<NB, 1024, 0, stream>>>(x, pos, tab,
                                                        W1a, b1a, W2a, b2a,
                                                        W1b, b1b, W2b, b2b,
                                                        W1c, b1c, W2c, b2c,
                                                        Wr, br, out);
    } else {
        megafused_kernel<false><<<NB, 1024, 0, stream>>>(x, pos, tab,
                                                         W1a, b1a, W2a, b2a,
                                                         W1b, b1b, W2b, b2b,
                                                         W1c, b1c, W2c, b2c,
                                                         Wr, br, out);
    }
}

// Round 12
// 174.096 us; speedup vs baseline: 1.1140x; 1.0048x over previous
//
#include <hip/hip_runtime.h>
#include <cstddef>
#include <cstdint>

#define NB 256     // graphs
#define M 512      // nodes per graph
#define KNN 6      // neighbors
#define C 32       // channels

// ---------------------------------------------------------------------------
// Round-22 = round-11 structure (scalar/broadcast-path scan + two 64 KB LDS
// buffers, 10 barriers, dispatch ~95us, VGPR 56, no spill) with the pre-
// kernel DELETED: each block builds its own graph's 8 KB float4 table slice
// {x,y,z,|p|^2} in-kernel (same norm fma chain), then reads it back with
// uniform-address vector loads.
//  - 1 block = 1 CU: writes are write-through to L2 + invalidate own L1 line;
//    __syncthreads drains vmcnt(0) before s_barrier => post-barrier reads on
//    the same CU are coherent. No scalar-cache exposure (aliasing store
//    prevents s_load scalarization -> uniform vector broadcast, L1-resident).
//  - LDS pipe stays free during the scan (round-11's win).
//  - removes the build_table dispatch (~10-15us of serialized bench time).
// All fp chains bit-identical to validated round-11: table norm chain, scan
// dist fma form + candidate order, med3 strict-< ascending insert, gather
// fmax k=0..5 order, MLP fma i=0..31 order, relu-fold via 0-init, self-loop
// union pool identity.
// ---------------------------------------------------------------------------

template <bool USE_TAB>
__global__ __launch_bounds__(1024, 1) void megafused_kernel(
    const float* __restrict__ x, const float* __restrict__ pos,
    float4* __restrict__ tab,
    const float* __restrict__ W1a, const float* __restrict__ b1a,
    const float* __restrict__ W2a, const float* __restrict__ b2a,
    const float* __restrict__ W1b, const float* __restrict__ b1b,
    const float* __restrict__ W2b, const float* __restrict__ b2b,
    const float* __restrict__ W1c, const float* __restrict__ b1c,
    const float* __restrict__ W2c, const float* __restrict__ b2c,
    const float* __restrict__ Wr,  const float* __restrict__ br,
    float* __restrict__ out)
{
    __shared__ __align__(16) float Pbuf[M * C];   // 64 KB: T1, m1(L3), T3
    __shared__ __align__(16) float Qbuf[M * C];   // 64 KB: sp/lists, h, m1(L2), T2, pool
    const int g  = blockIdx.x;
    const int t  = threadIdx.x;
    const int n  = t & (M - 1);                 // node 0..511
    const int hv = t >> 9;                      // 0/1, wave-uniform
    const int c0 = __builtin_amdgcn_readfirstlane(hv << 4); // SGPR half base

    float4* sp    = (float4*)Qbuf;            // [0, 8K) B of Q (fallback only)
    float4* lists = (float4*)(Qbuf + 2048);   // [8K, 40K) B of Q

    // === phase 0: build this graph's table slice (or LDS fallback) ===
    float4* tabg = tab + (size_t)g * M;
    const float* p = pos + (size_t)g * M * 3;
    if (t < M) {
        float xx = p[3*t], yy = p[3*t+1], zz = p[3*t+2];
        const float4 pv = make_float4(xx, yy, zz, fmaf(xx, xx, fmaf(yy, yy, zz * zz)));
        if constexpr (USE_TAB) tabg[t] = pv;   // own-CU L1/L2, drained at barrier
        else                   sp[t]   = pv;
    }
    const float h0 = x[(size_t)g * M + n];     // early global load (used in L1)
    __syncthreads();                           // [bar] table/sp visible
    const float4 pm = USE_TAB ? tabg[n] : sp[n];

    // === phase 1: KNN scan — row n, cols [hv*256, hv*256+256) ===
    float d0 = INFINITY, d1 = INFINITY, d2 = INFINITY,
          d3 = INFINITY, d4 = INFINITY, d5 = INFINITY;
    int   i0 = -1, i1 = -1, i2 = -1, i3 = -1, i4 = -1, i5 = -1;

#pragma unroll 8
    for (int jj = 0; jj < 256; jj++) {
        const int col = (c0 << 4) + jj;        // uniform provenance (c0 is SGPR)
        float4 pn;
        if constexpr (USE_TAB) pn = tabg[col]; // uniform vector broadcast (L1)
        else                   pn = sp[col];   // wave-uniform LDS broadcast
        float dot  = fmaf(pm.x, pn.x, fmaf(pm.y, pn.y, pm.z * pn.z));
        float dist = fmaf(-2.f, dot, pm.w + pn.w);       // validated rounding chain
        bool c5 = dist < d5, c4 = dist < d4, c3 = dist < d3,
             c2 = dist < d2, c1 = dist < d1, cz = dist < d0;
        i5 = c4 ? i4 : (c5 ? col : i5);
        i4 = c3 ? i3 : (c4 ? col : i4);
        i3 = c2 ? i2 : (c3 ? col : i3);
        i2 = c1 ? i1 : (c2 ? col : i2);
        i1 = cz ? i0 : (c1 ? col : i1);
        i0 = cz ? col : i0;
        d5 = __builtin_amdgcn_fmed3f(dist, d4, d5);
        d4 = __builtin_amdgcn_fmed3f(dist, d3, d4);
        d3 = __builtin_amdgcn_fmed3f(dist, d2, d3);
        d2 = __builtin_amdgcn_fmed3f(dist, d1, d2);
        d1 = __builtin_amdgcn_fmed3f(dist, d0, d1);
        d0 = fminf(dist, d0);
    }

    // publish packed list: {d0..d5, pack(i0,i1,i2), pack(i3,i4,i5)} = 32 B
    {
        unsigned pa = (unsigned)i0 | ((unsigned)i1 << 10) | ((unsigned)i2 << 20);
        unsigned pb = (unsigned)i3 | ((unsigned)i4 << 10) | ((unsigned)i5 << 20);
        lists[2*t]     = make_float4(d0, d1, d2, d3);
        lists[2*t + 1] = make_float4(d4, d5, __uint_as_float(pa), __uint_as_float(pb));
    }
    __syncthreads();                           // [bar] lists visible

    // === phase 2: merge — base = half-0 list, insert half-1 (tie-stable:
    // half-0 columns have lower indices; strict-< keeps base on ties) ===
    int j[KNN];
    {
        const int pt = t ^ M;                       // partner thread
        const float4 q0 = lists[2*pt], q1 = lists[2*pt + 1];
        const unsigned ppa = __float_as_uint(q1.z), ppb = __float_as_uint(q1.w);

        float md[KNN]; int mi[KNN]; float sd[KNN]; int si[KNN];
        if (c0 == 0) {      // scalar branch: own = half0 (base), partner = half1
            md[0]=d0; md[1]=d1; md[2]=d2; md[3]=d3; md[4]=d4; md[5]=d5;
            mi[0]=i0; mi[1]=i1; mi[2]=i2; mi[3]=i3; mi[4]=i4; mi[5]=i5;
            sd[0]=q0.x; sd[1]=q0.y; sd[2]=q0.z; sd[3]=q0.w; sd[4]=q1.x; sd[5]=q1.y;
            si[0]=(int)(ppa & 1023); si[1]=(int)((ppa >> 10) & 1023); si[2]=(int)((ppa >> 20) & 1023);
            si[3]=(int)(ppb & 1023); si[4]=(int)((ppb >> 10) & 1023); si[5]=(int)((ppb >> 20) & 1023);
        } else {            // own = half1 (insert), partner = half0 (base)
            md[0]=q0.x; md[1]=q0.y; md[2]=q0.z; md[3]=q0.w; md[4]=q1.x; md[5]=q1.y;
            mi[0]=(int)(ppa & 1023); mi[1]=(int)((ppa >> 10) & 1023); mi[2]=(int)((ppa >> 20) & 1023);
            mi[3]=(int)(ppb & 1023); mi[4]=(int)((ppb >> 10) & 1023); mi[5]=(int)((ppb >> 20) & 1023);
            sd[0]=d0; sd[1]=d1; sd[2]=d2; sd[3]=d3; sd[4]=d4; sd[5]=d5;
            si[0]=i0; si[1]=i1; si[2]=i2; si[3]=i3; si[4]=i4; si[5]=i5;
        }
#pragma unroll
        for (int k = 0; k < KNN; k++) {
            const float dist = sd[k];
            const int   nn   = si[k];
            bool c5m = dist < md[5], c4m = dist < md[4], c3m = dist < md[3],
                 c2m = dist < md[2], c1m = dist < md[1], czm = dist < md[0];
            mi[5] = c4m ? mi[4] : (c5m ? nn : mi[5]);
            mi[4] = c3m ? mi[3] : (c4m ? nn : mi[4]);
            mi[3] = c2m ? mi[2] : (c3m ? nn : mi[3]);
            mi[2] = c1m ? mi[1] : (c2m ? nn : mi[2]);
            mi[1] = czm ? mi[0] : (c1m ? nn : mi[1]);
            mi[0] = czm ? nn : mi[0];
            md[5] = __builtin_amdgcn_fmed3f(dist, md[4], md[5]);
            md[4] = __builtin_amdgcn_fmed3f(dist, md[3], md[4]);
            md[3] = __builtin_amdgcn_fmed3f(dist, md[2], md[3]);
            md[2] = __builtin_amdgcn_fmed3f(dist, md[1], md[2]);
            md[1] = __builtin_amdgcn_fmed3f(dist, md[0], md[1]);
            md[0] = fminf(dist, md[0]);
        }
#pragma unroll
        for (int k = 0; k < KNN; k++) j[k] = mi[k];
    }
    // no barrier: lists (Q) are not overwritten until layer-2 phase B, which
    // is ordered after the T1-visible barrier below (program order per thread)

    // ---- precomputed addressing (byte offsets, round-4 formulas) ----
    const int ne     = n & 3;
    const int nb_own = (n << 7) + ((hv ^ ((n >> 2) & 1)) << 6);
    const int nb_par = nb_own ^ 64;

    int jb[KNN], je[KNN];
#pragma unroll
    for (int k = 0; k < KNN; k++) {
        const int jl = j[k];
        jb[k] = (jl << 7) + ((hv ^ ((jl >> 2) & 1)) << 6);
        je[k] = jl & 3;
    }

    // === layer 1: T1 = MLP_a([x,pos]) -> P ===
    {
        const float h1 = pm.x, h2 = pm.y, h3 = pm.z;
        float m1[C];
#pragma unroll
        for (int o = 0; o < C; o++) {
            float a = b1a[o];
            a = fmaf(W1a[o*4+0], h0, a);
            a = fmaf(W1a[o*4+1], h1, a);
            a = fmaf(W1a[o*4+2], h2, a);
            a = fmaf(W1a[o*4+3], h3, a);
            m1[o] = fmaxf(a, 0.f);
        }
#pragma unroll
        for (int q2 = 0; q2 < 4; q2++) {
            float4 v; float* vp = &v.x;
#pragma unroll
            for (int u = 0; u < 4; u++) {
                const int o = c0 + q2*4 + u;
                float a = b2a[o];
#pragma unroll
                for (int i = 0; i < C; i++) a = fmaf(W2a[o*C + i], m1[i], a);
                vp[u] = a;
            }
            *(float4*)((char*)Pbuf + nb_own + ((q2 ^ ne) << 4)) = v;
        }
    }
    __syncthreads();                           // [bar] T1 visible; lists dead

    // === layers 2,3: 3 barriers each; src holds T_in, dst holds h then T_out,
    // m1 staged into src (T_in dead after the h barrier) ===
#pragma unroll 1
    for (int layer = 0; layer < 2; layer++) {
        const float* W1 = layer ? W1c : W1b;
        const float* b1 = layer ? b1c : b1b;
        const float* W2 = layer ? W2c : W2b;
        const float* b2 = layer ? b2c : b2b;
        char* src = (char*)(layer ? Qbuf : Pbuf);   // T_in; then m1 staging
        char* dst = (char*)(layer ? Pbuf : Qbuf);   // h staging; then T_out

        // A: aggregate neighbors' half-rows from src; 0-init folds relu (exact)
        float hm[16];
#pragma unroll
        for (int u = 0; u < 16; u++) hm[u] = 0.f;
#pragma unroll
        for (int k = 0; k < KNN; k++) {
#pragma unroll
            for (int q2 = 0; q2 < 4; q2++) {
                const float4 v = *(const float4*)(src + jb[k] + ((q2 ^ je[k]) << 4));
                hm[4*q2+0] = fmaxf(hm[4*q2+0], v.x);
                hm[4*q2+1] = fmaxf(hm[4*q2+1], v.y);
                hm[4*q2+2] = fmaxf(hm[4*q2+2], v.z);
                hm[4*q2+3] = fmaxf(hm[4*q2+3], v.w);
            }
        }
        // B: write h half-row to dst (no alias with src reads)
#pragma unroll
        for (int q2 = 0; q2 < 4; q2++)
            *(float4*)(dst + nb_own + ((q2 ^ ne) << 4)) =
                make_float4(hm[4*q2+0], hm[4*q2+1], hm[4*q2+2], hm[4*q2+3]);
        __syncthreads();              // [bar] h visible; all T_in reads done
        // C: own half from regs, read only PARTNER's 4 quads from dst
        float hf[C];
        if (c0 == 0) {
#pragma unroll
            for (int u = 0; u < 16; u++) hf[u] = hm[u];
#pragma unroll
            for (int q2 = 0; q2 < 4; q2++) {
                const float4 v = *(const float4*)(dst + nb_par + ((q2 ^ ne) << 4));
                hf[16+4*q2+0]=v.x; hf[16+4*q2+1]=v.y; hf[16+4*q2+2]=v.z; hf[16+4*q2+3]=v.w;
            }
        } else {
#pragma unroll
            for (int u = 0; u < 16; u++) hf[16+u] = hm[u];
#pragma unroll
            for (int q2 = 0; q2 < 4; q2++) {
                const float4 v = *(const float4*)(dst + nb_par + ((q2 ^ ne) << 4));
                hf[4*q2+0]=v.x; hf[4*q2+1]=v.y; hf[4*q2+2]=v.z; hf[4*q2+3]=v.w;
            }
        }
        // D: m1 HALF (16 outs x 32 ins) -> stage into src (T_in dead)
        float m1h[16];
#pragma unroll
        for (int o2 = 0; o2 < 16; o2++) {
            const int o = c0 + o2;
            float a = b1[o];
#pragma unroll
            for (int i = 0; i < C; i++) a = fmaf(W1[o*C + i], hf[i], a);
            m1h[o2] = fmaxf(a, 0.f);
        }
#pragma unroll
        for (int q2 = 0; q2 < 4; q2++)
            *(float4*)(src + nb_own + ((q2 ^ ne) << 4)) =
                make_float4(m1h[4*q2+0], m1h[4*q2+1], m1h[4*q2+2], m1h[4*q2+3]);
        __syncthreads();              // [bar] m1 visible; all h reads done
        // E: own half from regs, read only PARTNER's 4 quads from src
        float m1f[C];
        if (c0 == 0) {
#pragma unroll
            for (int u = 0; u < 16; u++) m1f[u] = m1h[u];
#pragma unroll
            for (int q2 = 0; q2 < 4; q2++) {
                const float4 v = *(const float4*)(src + nb_par + ((q2 ^ ne) << 4));
                m1f[16+4*q2+0]=v.x; m1f[16+4*q2+1]=v.y; m1f[16+4*q2+2]=v.z; m1f[16+4*q2+3]=v.w;
            }
        } else {
#pragma unroll
            for (int u = 0; u < 16; u++) m1f[16+u] = m1h[u];
#pragma unroll
            for (int q2 = 0; q2 < 4; q2++) {
                const float4 v = *(const float4*)(src + nb_par + ((q2 ^ ne) << 4));
                m1f[4*q2+0]=v.x; m1f[4*q2+1]=v.y; m1f[4*q2+2]=v.z; m1f[4*q2+3]=v.w;
            }
        }
        // F: T_out half-row -> dst (h region dead: all C reads done at m1 bar)
#pragma unroll
        for (int q2 = 0; q2 < 4; q2++) {
            float4 v; float* vp = &v.x;
#pragma unroll
            for (int u = 0; u < 4; u++) {
                const int o = c0 + q2*4 + u;
                float a = b2[o];
#pragma unroll
                for (int i = 0; i < C; i++) a = fmaf(W2[o*C + i], m1f[i], a);
                vp[u] = a;
            }
            *(float4*)(dst + nb_own + ((q2 ^ ne) << 4)) = v;
        }
        __syncthreads();              // [bar] T_out visible
    }
    // T2 -> Q (layer 0), T3 -> P (layer 1); pool reads P, scratches Q.

    // === global max pool DIRECTLY over T3 (self-loop union identity,
    // validated round-4/11); relu folded via 0-init (exact) ===
    {
        const int c   = t & 31;        // channel
        const int grp = t >> 5;        // row group 0..31 (16 rows each)
        float m = 0.f;
#pragma unroll
        for (int r16 = 0; r16 < 16; r16++) {
            const int r = (grp << 4) + r16;
            m = fmaxf(m, Pbuf[(r << 5) + ((((c >> 2) ^ (r & 7)) << 2) | (c & 3))]);
        }
        Qbuf[(grp << 5) + (c ^ grp)] = m;        // partial -> Q (no alias w/ P reads)
        __syncthreads();               // [bar] partials visible
        if (t < 32) {                  // wave 0: 32 lanes finish the pool
            float mm = 0.f;
#pragma unroll
            for (int g2 = 0; g2 < 32; g2++)
                mm = fmaxf(mm, Qbuf[(g2 << 5) + (t ^ g2)]);
            Qbuf[t] = mm;              // word t read first by lane t only (g2=0)
        }
        __syncthreads();               // [bar] finals visible
    }

    // === head ===
    if (t < 6) {
        float a = br[t];
#pragma unroll
        for (int i = 0; i < C; i++) a = fmaf(Wr[t*C + i], Qbuf[i], a);
        out[g * 6 + t] = a;
    }
}

extern "C" void kernel_launch(void* const* d_in, const int* in_sizes, int n_in,
                              void* d_out, int out_size, void* d_ws, size_t ws_size,
                              hipStream_t stream) {
    const float* x   = (const float*)d_in[0];
    const float* pos = (const float*)d_in[1];
    // d_in[2] = batch (int64) unused: nodes are contiguous M-per-graph
    const float* W1a = (const float*)d_in[3];
    const float* b1a = (const float*)d_in[4];
    const float* W2a = (const float*)d_in[5];
    const float* b2a = (const float*)d_in[6];
    const float* W1b = (const float*)d_in[7];
    const float* b1b = (const float*)d_in[8];
    const float* W2b = (const float*)d_in[9];
    const float* b2b = (const float*)d_in[10];
    const float* W1c = (const float*)d_in[11];
    const float* b1c = (const float*)d_in[12];
    const float* W2c = (const float*)d_in[13];
    const float* b2c = (const float*)d_in[14];
    const float* Wr  = (const float*)d_in[15];
    const float* br  = (const float*)d_in[16];

    float* out = (float*)d_out;
    float4* tab = (float4*)d_ws;
    const bool use_tab = (d_ws != nullptr) &&
                         (ws_size >= sizeof(float4) * (size_t)NB * M);

    if (use_tab) {
        megafused_kernel<true><<<NB, 1024, 0, stream>>>(x, pos, tab,
                                                        W1a, b1a, W2a, b2a,
                                                        W1b, b1b, W2b, b2b,
                                                        W1c, b1c, W2c, b2c,
                                                        Wr, br, out);
    } else {
        megafused_kernel<false><<<NB, 1024, 0, stream>>>(x, pos, tab,
                                                         W1a, b1a, W2a, b2a,
                                                         W1b, b1b, W2b, b2b,
                                                         W1c, b1c, W2c, b2c,
                                                         Wr, br, out);
    }
}